// Round 9
// baseline (29.230 us; speedup 1.0000x reference)
//
#include <hip/hip_runtime.h>
#include <math.h>
#include <float.h>

#define B 32
#define N 2048
#define EPS 1e-6f
#define T1 128                // threads per stage-1 block
#define Q 8                   // queries per thread
#define CHUNK 128             // refs per block
#define C 16                  // ref chunks (N/CHUNK)
#define NQ_TOTAL (2 * B * N)  // 131072 query slots

// Stage 1: thread owns Q=8 queries (in regs), block stages one 128-ref chunk
// expanded to SoA-by-4 (X=-2x, Y=-2y, Crr=|r|^2) in 6 KB LDS. Inner loop: per
// 4-ref group, 3 broadcast ds_read_b128 serve all 8 queries -> LDS cost/pair
// cut 4x vs Q=2 (the measured R2-R8 wall). t=|r|^2-2q.r min-chained per query;
// |q|^2 added at the end (constant per query, commutes with min).
__global__ __launch_bounds__(128) void chamfer_minq8_kernel(
    const float* __restrict__ pred, const float* __restrict__ target,
    float* __restrict__ pmin) {
  const int c  = blockIdx.x;    // 0..15 ref chunk
  const int qg = blockIdx.y;    // 0..127 query group (1024 queries)
  const int db = qg >> 1;       // 0..63 : dir*32 + b
  const int half = qg & 1;
  const int dir = db >> 5;
  const int b   = db & 31;

  const float* qraw = (dir ? target : pred) + (size_t)b * N * 2;
  const float* rraw = (dir ? pred : target) + (size_t)b * N * 2;

  __shared__ float Lf[3 * CHUNK];   // 1536 B? no: 384 floats = 1536 B... (see layout: 12 floats per 4-ref group x 32 groups)

  // stage+expand: thread i handles ref c*128+i -> group g=i>>2, slot e=i&3
  {
    const float2 rv = ((const float2*)rraw)[c * CHUNK + threadIdx.x];
    const int g = threadIdx.x >> 2, e = threadIdx.x & 3;
    Lf[12 * g + e]     = -2.f * rv.x;
    Lf[12 * g + 4 + e] = -2.f * rv.y;
    Lf[12 * g + 8 + e] = fmaf(rv.x, rv.x, rv.y * rv.y);
  }
  __syncthreads();

  // load Q=8 queries: qslot = half*1024 + k*128 + tid (coalesced)
  float qx[Q], qy[Q], m[Q];
#pragma unroll
  for (int k = 0; k < Q; ++k) {
    const float2 qp = ((const float2*)qraw)[half * 1024 + k * T1 + threadIdx.x];
    qx[k] = qp.x;
    qy[k] = qp.y;
    m[k] = FLT_MAX;
  }

#pragma unroll 4
  for (int jj = 0; jj < CHUNK / 4; ++jj) {   // 32 iters, 4 refs each
    const float4 X = *(const float4*)(Lf + 12 * jj);
    const float4 Y = *(const float4*)(Lf + 12 * jj + 4);
    const float4 Cr = *(const float4*)(Lf + 12 * jj + 8);
#pragma unroll
    for (int k = 0; k < Q; ++k) {
      float d0 = fmaf(X.x, qx[k], fmaf(Y.x, qy[k], Cr.x));
      float d1 = fmaf(X.y, qx[k], fmaf(Y.y, qy[k], Cr.y));
      float d2 = fmaf(X.z, qx[k], fmaf(Y.z, qy[k], Cr.z));
      float d3 = fmaf(X.w, qx[k], fmaf(Y.w, qy[k], Cr.w));
      m[k] = fminf(fminf(m[k], d0), d1);   // v_min3
      m[k] = fminf(fminf(m[k], d2), d3);   // v_min3
    }
  }

  // add |q|^2 and write per-chunk min (coalesced)
#pragma unroll
  for (int k = 0; k < Q; ++k) {
    const float qq = fmaf(qx[k], qx[k], qy[k] * qy[k]);
    pmin[(size_t)c * NQ_TOTAL + qg * 1024 + k * T1 + threadIdx.x] = m[k] + qq;
  }
}

// Stage 2: per-query min over 16 chunks, sqrt, block-sum.
__global__ __launch_bounds__(256) void chamfer_combine_kernel(
    const float* __restrict__ pmin, float* __restrict__ partial2) {
  const int q = blockIdx.x * 256 + threadIdx.x;  // 0..131071
  float v = FLT_MAX;
#pragma unroll
  for (int c = 0; c < C; ++c)
    v = fminf(v, pmin[(size_t)c * NQ_TOTAL + q]);
  float s = sqrtf(fmaxf(v, 0.f) + EPS);
#pragma unroll
  for (int off = 32; off > 0; off >>= 1)
    s += __shfl_down(s, off, 64);
  __shared__ float wsum[4];
  if ((threadIdx.x & 63) == 0) wsum[threadIdx.x >> 6] = s;
  __syncthreads();
  if (threadIdx.x == 0)
    partial2[blockIdx.x] = wsum[0] + wsum[1] + wsum[2] + wsum[3];
}

// Stage 3: final 512-way reduce, scale, write scalar.
__global__ __launch_bounds__(512) void chamfer_final_kernel(
    const float* __restrict__ partial2, float* __restrict__ out) {
  float v = partial2[threadIdx.x];
#pragma unroll
  for (int off = 32; off > 0; off >>= 1)
    v += __shfl_down(v, off, 64);
  __shared__ float wsum[8];
  if ((threadIdx.x & 63) == 0) wsum[threadIdx.x >> 6] = v;
  __syncthreads();
  if (threadIdx.x == 0) {
    float s = 0.f;
#pragma unroll
    for (int i = 0; i < 8; ++i) s += wsum[i];
    out[0] = s * (1.0f / (float)(B * N));
  }
}

extern "C" void kernel_launch(void* const* d_in, const int* in_sizes, int n_in,
                              void* d_out, int out_size, void* d_ws, size_t ws_size,
                              hipStream_t stream) {
  const float* pred   = (const float*)d_in[0];
  const float* target = (const float*)d_in[1];
  float* out = (float*)d_out;

  float* pmin     = (float*)d_ws;                        // 16*131072 f32 = 8 MB
  float* partial2 = (float*)d_ws + (size_t)C * NQ_TOTAL; // 512 f32

  dim3 grid1(C, 2 * B * N / (T1 * Q));   // (16,128) = 2048 blocks
  chamfer_minq8_kernel<<<grid1, T1, 0, stream>>>(pred, target, pmin);
  chamfer_combine_kernel<<<NQ_TOTAL / 256, 256, 0, stream>>>(pmin, partial2);
  chamfer_final_kernel<<<1, 512, 0, stream>>>(partial2, out);
}